// Round 2
// baseline (301.772 us; speedup 1.0000x reference)
//
#include <hip/hip_runtime.h>
#include <cstddef>

#define NEG_INIT -1.0e9f

typedef _Float16 f16x8 __attribute__((ext_vector_type(8)));
typedef _Float16 f16x4 __attribute__((ext_vector_type(4)));
typedef float f32x4 __attribute__((ext_vector_type(4)));

constexpr int D   = 512;   // feature dim
constexpr int BM  = 32;    // rows per block
constexpr int BK  = 32;    // K per step
constexpr int NKS = D / BK;   // 16
constexpr int LDX = 40;    // padded fp16 row of X K-slice (80 B)
constexpr int LDF = 516;   // padded fp32 retained row
constexpr int PS  = 516;   // partial slot stride (floats): [m, s, pad, pad, f[512]]

// Raw workgroup barrier WITHOUT the vmcnt(0) drain __syncthreads() emits.
// LDS producer/consumer safety comes from lgkmcnt(0); global loads are
// reg-staged (never write LDS), so vmcnt may stay outstanding across the
// barrier -- the counted-vmcnt pattern (guide T4 / m201 template).
#define BAR_LGKM()                                            \
    do {                                                      \
        asm volatile("s_waitcnt lgkmcnt(0)" ::: "memory");    \
        __builtin_amdgcn_s_barrier();                         \
        asm volatile("" ::: "memory");                        \
    } while (0)

// ---------------------------------------------------------------------------
// k_wprep: fragment-major fp16 weights.
//   Wfrag[(((wc*16 + ks)*4 + j)*64 + lane)*8 + e] =
//     row(wc,j,lane&15)[ks*32 + (lane>>4)*8 + e]
//   where row = Vw[wc*32 + j*16 + l15]      (j<2)
//             = Uw[wc*32 + (j-2)*16 + l15]  (j>=2)
// Grid: 256 blocks (bid = wc*64 + ks*4 + j) x 64 threads (lane).
// ---------------------------------------------------------------------------
__global__ __launch_bounds__(64) void k_wprep(const float* __restrict__ Vw,
                                              const float* __restrict__ Uw,
                                              _Float16* __restrict__ Wfrag) {
    const int bid  = blockIdx.x;
    const int lane = threadIdx.x;
    const int j    = bid & 3;
    const int ks   = (bid >> 2) & 15;
    const int wc   = bid >> 6;
    const int l15  = lane & 15;
    const int kgrp = lane >> 4;
    const float* src = (j < 2 ? Vw + (size_t)(wc * 32 + j * 16 + l15) * D
                              : Uw + (size_t)(wc * 32 + (j - 2) * 16 + l15) * D)
                       + ks * BK + kgrp * 8;
    f16x8 h;
    #pragma unroll
    for (int e = 0; e < 8; ++e) h[e] = (_Float16)src[e];
    *(f16x8*)(Wfrag + ((size_t)bid * 64 + lane) * 8) = h;
}

// ---------------------------------------------------------------------------
// k_bounds: start[g] = lower_bound(index, g), g in [0, G].
// ---------------------------------------------------------------------------
__global__ __launch_bounds__(256) void k_bounds(const int* __restrict__ index,
                                                int N, int G,
                                                int* __restrict__ start) {
    int g = blockIdx.x * blockDim.x + threadIdx.x;
    if (g > G) return;
    int lo = 0, hi = N;
    while (lo < hi) {
        int mid = (lo + hi) >> 1;
        if (index[mid] < g) lo = mid + 1; else hi = mid;
    }
    start[g] = lo;
}

// ---------------------------------------------------------------------------
// k_fused: 32-row block, 256 threads (4 waves, one wave-col each of 64 GEMM
// cols). fp16 MFMA GEMM (X double-buffered in LDS, B direct from L2-resident
// Wfrag) -> gated scores -> wave-parallel per-segment softmax partials ->
// pooling partials from the fp32 LDS-retained copy of this block's rows
// (XF) -- feats is read from HBM exactly ONCE.
// K-loop barriers are raw s_barrier + lgkmcnt(0) ONLY: the 4-deep reg
// prefetch ring stays in flight across barriers (counted vmcnt), instead of
// being drained every step by __syncthreads()'s vmcnt(0).
// ---------------------------------------------------------------------------
__global__ __launch_bounds__(256, 2) void k_fused(
    const float* __restrict__ feats, const _Float16* __restrict__ Wfrag,
    const float* __restrict__ Vb, const float* __restrict__ Ub,
    const float* __restrict__ ww, const int* __restrict__ index,
    const int* __restrict__ start, float* __restrict__ P, int N)
{
    __shared__ __align__(16) _Float16 Xs[2][BM][LDX];   // 5120 B
    __shared__ __align__(16) float XF[BM][LDF];         // 66048 B fp32 retention
    __shared__ float sred[4][BM];                       //   512 B
    __shared__ float srow[BM];
    __shared__ float evals[BM];

    const int t    = threadIdx.x;
    const int lane = t & 63;
    const int wc   = t >> 6;     // wave-col 0..3
    const int l15  = lane & 15;
    const int kgrp = lane >> 4;  // 0..3
    const int blk  = blockIdx.x;
    const int rb   = blk * BM;

    // staging map: thread t loads row t>>3, cols (t&7)*4..+3 of each K slice
    const int xrow = t >> 3;     // 0..31
    const int xc4  = t & 7;      // 0..7
    const float* xg = feats + (size_t)min(rb + xrow, N - 1) * D + xc4 * 4;

    f32x4 acc[2][4];
    #pragma unroll
    for (int i = 0; i < 2; ++i)
        #pragma unroll
        for (int j = 0; j < 4; ++j) acc[i][j] = (f32x4){0.f, 0.f, 0.f, 0.f};

    float4 xa[4];   // 4-deep A prefetch ring
    auto issueA = [&](int ks) {
        xa[ks & 3] = *(const float4*)(xg + ks * BK);
    };
    auto commitA = [&](int ks) {
        float4 a = xa[ks & 3];
        f16x4 h = { (_Float16)a.x, (_Float16)a.y, (_Float16)a.z, (_Float16)a.w };
        *(f16x4*)&Xs[ks & 1][xrow][xc4 * 4] = h;
        *(f32x4*)&XF[xrow][ks * BK + xc4 * 4] = (f32x4){a.x, a.y, a.z, a.w};
    };

    issueA(0); issueA(1); issueA(2); issueA(3);
    commitA(0);
    BAR_LGKM();

    // per-(wc,lane) base into fragment-major weights
    const _Float16* wbase = Wfrag + (size_t)wc * 64 * 512 + (size_t)lane * 8;

    for (int ks = 0; ks < NKS; ++ks) {
        f16x8 bf[4], af[2];
        #pragma unroll
        for (int j = 0; j < 4; ++j)
            bf[j] = *(const f16x8*)(wbase + (size_t)(ks * 4 + j) * 512);
        #pragma unroll
        for (int i = 0; i < 2; ++i)
            af[i] = *(const f16x8*)&Xs[ks & 1][i * 16 + l15][kgrp * 8];
        if (ks + 4 < NKS) issueA(ks + 4);   // HBM load 4 steps ahead
        #pragma unroll
        for (int i = 0; i < 2; ++i)
            #pragma unroll
            for (int j = 0; j < 4; ++j)
                acc[i][j] = __builtin_amdgcn_mfma_f32_16x16x32_f16(
                    af[i], bf[j], acc[i][j], 0, 0, 0);
        if (ks + 1 < NKS) commitA(ks + 1);  // write-late into other buffer
        BAR_LGKM();
    }

    // ---- gated epilogue -> per-row scores ----
    float part[2][4];
    #pragma unroll
    for (int i = 0; i < 2; ++i)
        #pragma unroll
        for (int r = 0; r < 4; ++r) part[i][r] = 0.f;

    #pragma unroll
    for (int j = 0; j < 2; ++j) {
        int c = wc * 32 + j * 16 + l15;    // attention col 0..127
        float vb = Vb[c], ub = Ub[c], w = ww[c];
        #pragma unroll
        for (int i = 0; i < 2; ++i)
            #pragma unroll
            for (int r = 0; r < 4; ++r) {
                float v = acc[i][j][r] + vb;
                float u = acc[i][j + 2][r] + ub;
                part[i][r] += w * tanhf(v) * (1.f / (1.f + expf(-u)));
            }
    }
    #pragma unroll
    for (int off = 1; off < 16; off <<= 1)
        #pragma unroll
        for (int i = 0; i < 2; ++i)
            #pragma unroll
            for (int r = 0; r < 4; ++r)
                part[i][r] += __shfl_xor(part[i][r], off);

    if (l15 == 0) {
        #pragma unroll
        for (int i = 0; i < 2; ++i)
            #pragma unroll
            for (int r = 0; r < 4; ++r)
                sred[wc][i * 16 + kgrp * 4 + r] = part[i][r];
    }
    __syncthreads();
    if (t < BM)
        srow[t] = sred[0][t] + sred[1][t] + sred[2][t] + sred[3][t];
    __syncthreads();

    // ---- wave-parallel per-segment softmax partials (no barriers inside) ----
    const int gl = index[rb];
    const int gh = index[rb + BM - 1];
    for (int g = gl + wc; g <= gh; g += 4) {
        const int r0 = max(start[g], rb), r1 = min(start[g + 1], rb + BM);
        if (r1 <= r0) continue;
        const bool in = (lane >= r0 - rb) && (lane < r1 - rb);
        float m = in ? srow[lane] : NEG_INIT;
        #pragma unroll
        for (int off = 32; off; off >>= 1) m = fmaxf(m, __shfl_xor(m, off));
        float e = in ? expf(srow[lane] - m) : 0.f;
        if (in) evals[lane] = e;
        float s = e;
        #pragma unroll
        for (int off = 32; off; off >>= 1) s += __shfl_xor(s, off);
        if (lane == 0) {
            float* slot = P + (size_t)(blk + g) * PS;
            slot[0] = m; slot[1] = s;
        }
    }
    __syncthreads();

    // ---- pooling partials from the LDS-retained fp32 rows (no HBM re-read) ----
    for (int g = gl; g <= gh; ++g) {
        const int r0 = max(start[g], rb), r1 = min(start[g + 1], rb + BM);
        if (r1 <= r0) continue;
        float ax = 0.f, ay = 0.f;
        for (int r = r0; r < r1; ++r) {
            float e = evals[r - rb];                       // LDS broadcast
            float2 x = *(const float2*)&XF[r - rb][t * 2]; // LDS, conflict-free
            ax = fmaf(e, x.x, ax);
            ay = fmaf(e, x.y, ay);
        }
        float2 o = {ax, ay};
        *(float2*)(P + (size_t)(blk + g) * PS + 4 + t * 2) = o;
    }
}

// ---------------------------------------------------------------------------
// k_merge: combine per-block segment partials; one block per group, t = col.
// ---------------------------------------------------------------------------
__global__ __launch_bounds__(512) void k_merge(const float* __restrict__ P,
                                               const int* __restrict__ start,
                                               float* __restrict__ out)
{
    const int g = blockIdx.x, t = threadIdx.x;
    const int s0 = start[g], s1 = start[g + 1];
    if (s0 >= s1) { out[(size_t)g * D + t] = 0.f; return; }
    const int b0 = s0 >> 5, b1 = (s1 - 1) >> 5;   // BM = 32
    float M = NEG_INIT;
    for (int b = b0; b <= b1; ++b)
        M = fmaxf(M, P[(size_t)(b + g) * PS]);
    float den = 0.f, acc = 0.f;
    for (int b = b0; b <= b1; ++b) {
        const float* slot = P + (size_t)(b + g) * PS;
        float w = expf(slot[0] - M);
        den += w * slot[1];
        acc += w * slot[4 + t];
    }
    out[(size_t)g * D + t] = acc / (den + 1e-8f);
}

// ---------------------------------------------------------------------------
extern "C" void kernel_launch(void* const* d_in, const int* in_sizes, int n_in,
                              void* d_out, int out_size, void* d_ws, size_t ws_size,
                              hipStream_t stream) {
    const float* feats = (const float*)d_in[0];
    const int*   index = (const int*)d_in[1];
    const float* Vw = (const float*)d_in[3];
    const float* Vb = (const float*)d_in[4];
    const float* Uw = (const float*)d_in[5];
    const float* Ub = (const float*)d_in[6];
    const float* ww = (const float*)d_in[7];
    float* out = (float*)d_out;

    const int N = in_sizes[1];          // 262144
    const int G = out_size / D;         // 512
    const int nblk = (N + BM - 1) / BM; // 8192

    // ws: Wfrag fp16[256*512] | start[G+1] | (16B align) | P[(nblk+G)*PS]
    _Float16* Wfrag = (_Float16*)d_ws;
    int* start      = (int*)(Wfrag + (size_t)256 * 512);
    size_t off      = (size_t)256 * 512 * 2 + (G + 1) * 4;
    off             = (off + 15) & ~(size_t)15;
    float* P        = (float*)((char*)d_ws + off);

    hipLaunchKernelGGL(k_wprep, dim3(256), dim3(64), 0, stream, Vw, Uw, Wfrag);
    hipLaunchKernelGGL(k_bounds, dim3((G + 1 + 255) / 256), dim3(256), 0, stream,
                       index, N, G, start);
    hipLaunchKernelGGL(k_fused, dim3(nblk), dim3(256), 0, stream,
                       feats, Wfrag, Vb, Ub, ww, index, start, P, N);
    hipLaunchKernelGGL(k_merge, dim3(G), dim3(512), 0, stream, P, start, out);
}

// Round 3
// 231.969 us; speedup vs baseline: 1.3009x; 1.3009x over previous
//
#include <hip/hip_runtime.h>
#include <cstddef>

#define NEG_INIT -1.0e9f

typedef _Float16 f16x8 __attribute__((ext_vector_type(8)));
typedef float f32x4 __attribute__((ext_vector_type(4)));

constexpr int D   = 512;   // feature dim
constexpr int BM  = 32;    // rows per block
constexpr int BK  = 32;    // K per MFMA step
constexpr int NKS = D / BK;   // 16
constexpr int LDF = 516;   // padded fp32 retained row (2064 B; 516%32=4 -> balanced banks)
constexpr int PS  = 516;   // partial slot stride (floats): [m, s, pad, pad, f[512]]

// ---------------------------------------------------------------------------
// k_wprep: fragment-major fp16 weights (unchanged layout).
//   Wfrag[(((wc4*16 + ks)*4 + j)*64 + lane)*8 + e] =
//     row(wc4,j,lane&15)[ks*32 + (lane>>4)*8 + e]
//   where row = Vw[wc4*32 + j*16 + l15]      (j<2)
//             = Uw[wc4*32 + (j-2)*16 + l15]  (j>=2)
// Grid: 256 blocks (bid = wc4*64 + ks*4 + j) x 64 threads (lane).
// ---------------------------------------------------------------------------
__global__ __launch_bounds__(64) void k_wprep(const float* __restrict__ Vw,
                                              const float* __restrict__ Uw,
                                              _Float16* __restrict__ Wfrag) {
    const int bid  = blockIdx.x;
    const int lane = threadIdx.x;
    const int j    = bid & 3;
    const int ks   = (bid >> 2) & 15;
    const int wc   = bid >> 6;
    const int l15  = lane & 15;
    const int kgrp = lane >> 4;
    const float* src = (j < 2 ? Vw + (size_t)(wc * 32 + j * 16 + l15) * D
                              : Uw + (size_t)(wc * 32 + (j - 2) * 16 + l15) * D)
                       + ks * BK + kgrp * 8;
    f16x8 h;
    #pragma unroll
    for (int e = 0; e < 8; ++e) h[e] = (_Float16)src[e];
    *(f16x8*)(Wfrag + ((size_t)bid * 64 + lane) * 8) = h;
}

// ---------------------------------------------------------------------------
// k_bounds: start[g] = lower_bound(index, g), g in [0, G].
// ---------------------------------------------------------------------------
__global__ __launch_bounds__(256) void k_bounds(const int* __restrict__ index,
                                                int N, int G,
                                                int* __restrict__ start) {
    int g = blockIdx.x * blockDim.x + threadIdx.x;
    if (g > G) return;
    int lo = 0, hi = N;
    while (lo < hi) {
        int mid = (lo + hi) >> 1;
        if (index[mid] < g) lo = mid + 1; else hi = mid;
    }
    start[g] = lo;
}

// ---------------------------------------------------------------------------
// k_fused v3: 32-row block, 512 threads (8 waves; wave wc owns att cols
// [wc*16, wc*16+16) for both V and U). Structure:
//   phase 1: cooperative stage of ALL 32x512 fp32 rows into XF (one barrier)
//   phase 2: barrier-FREE K-loop: af = ds_read from XF + f32->f16 cvt,
//            bf = global loads from L2-resident Wfrag, 4 MFMA / step.
//            No inter-wave lockstep; compiler software-pipelines freely.
//   phase 3: gated epilogue -> per-row scores -> per-segment softmax
//            partials -> pooling partials from XF (feats read from HBM ONCE).
// 16 waves/CU (2 blocks x 8 waves, LDS 67 KB) -> 4 waves/SIMD latency hiding.
// ---------------------------------------------------------------------------
__global__ __launch_bounds__(512, 4) void k_fused(
    const float* __restrict__ feats, const _Float16* __restrict__ Wfrag,
    const float* __restrict__ Vb, const float* __restrict__ Ub,
    const float* __restrict__ ww, const int* __restrict__ index,
    const int* __restrict__ start, float* __restrict__ P, int N)
{
    __shared__ __align__(16) float XF[BM][LDF];         // 66048 B fp32 retention
    __shared__ float sred[8][BM];                       //  1024 B
    __shared__ float srow[BM];
    __shared__ float evals[BM];

    const int t    = threadIdx.x;
    const int lane = t & 63;
    const int wc   = t >> 6;     // wave 0..7
    const int l15  = lane & 15;
    const int kgrp = lane >> 4;  // 0..3
    const int blk  = blockIdx.x;
    const int rb   = blk * BM;

    // ---- phase 1: stage all 32 rows x 512 cols fp32 into XF ----
    {
        const int xrow = t >> 4;          // 0..31
        const int xcb  = t & 15;          // float4 slot 0..15
        const float* xg = feats + (size_t)min(rb + xrow, N - 1) * D + xcb * 4;
        #pragma unroll
        for (int k = 0; k < 8; ++k) {
            f32x4 v = *(const f32x4*)(xg + k * 64);
            *(f32x4*)&XF[xrow][k * 64 + xcb * 4] = v;
        }
    }
    __syncthreads();

    // ---- phase 2: barrier-free MFMA K-loop ----
    // wave wc: V chunk j=(wc&1), U chunk j=2+(wc&1), col-quad wc>>1
    const _Float16* wbV = Wfrag + (size_t)(wc >> 1) * 32768
                                + (size_t)(wc & 1) * 512 + (size_t)lane * 8;
    const _Float16* wbU = wbV + 1024;

    f32x4 accV[2], accU[2];
    #pragma unroll
    for (int i = 0; i < 2; ++i) {
        accV[i] = (f32x4){0.f, 0.f, 0.f, 0.f};
        accU[i] = (f32x4){0.f, 0.f, 0.f, 0.f};
    }

    #pragma unroll 4
    for (int ks = 0; ks < NKS; ++ks) {
        f16x8 bv = *(const f16x8*)(wbV + (size_t)ks * 2048);
        f16x8 bu = *(const f16x8*)(wbU + (size_t)ks * 2048);
        f16x8 ha[2];
        #pragma unroll
        for (int i = 0; i < 2; ++i) {
            const float* xp = &XF[i * 16 + l15][ks * BK + kgrp * 8];
            f32x4 a0 = *(const f32x4*)xp;
            f32x4 a1 = *(const f32x4*)(xp + 4);
            ha[i] = (f16x8){ (_Float16)a0[0], (_Float16)a0[1],
                             (_Float16)a0[2], (_Float16)a0[3],
                             (_Float16)a1[0], (_Float16)a1[1],
                             (_Float16)a1[2], (_Float16)a1[3] };
        }
        #pragma unroll
        for (int i = 0; i < 2; ++i) {
            accV[i] = __builtin_amdgcn_mfma_f32_16x16x32_f16(ha[i], bv, accV[i], 0, 0, 0);
            accU[i] = __builtin_amdgcn_mfma_f32_16x16x32_f16(ha[i], bu, accU[i], 0, 0, 0);
        }
    }

    // ---- phase 3a: gated epilogue -> per-row scores ----
    {
        const int c = wc * 16 + l15;          // attention col 0..127
        const float vb = Vb[c], ub = Ub[c], w = ww[c];
        float part[2][4];
        #pragma unroll
        for (int i = 0; i < 2; ++i)
            #pragma unroll
            for (int r = 0; r < 4; ++r) {
                float v = accV[i][r] + vb;
                float u = accU[i][r] + ub;
                part[i][r] = w * tanhf(v) * (1.f / (1.f + expf(-u)));
            }
        #pragma unroll
        for (int off = 1; off < 16; off <<= 1)
            #pragma unroll
            for (int i = 0; i < 2; ++i)
                #pragma unroll
                for (int r = 0; r < 4; ++r)
                    part[i][r] += __shfl_xor(part[i][r], off);
        if (l15 == 0) {
            #pragma unroll
            for (int i = 0; i < 2; ++i)
                #pragma unroll
                for (int r = 0; r < 4; ++r)
                    sred[wc][i * 16 + kgrp * 4 + r] = part[i][r];
        }
    }
    __syncthreads();
    if (t < BM) {
        float s = sred[0][t];
        #pragma unroll
        for (int w8 = 1; w8 < 8; ++w8) s += sred[w8][t];
        srow[t] = s;
    }
    __syncthreads();

    // ---- phase 3b: wave-parallel per-segment softmax partials ----
    const int gl = index[rb];
    const int gh = index[rb + BM - 1];
    for (int g = gl + wc; g <= gh; g += 8) {
        const int r0 = max(start[g], rb), r1 = min(start[g + 1], rb + BM);
        if (r1 <= r0) continue;
        const bool in = (lane >= r0 - rb) && (lane < r1 - rb);
        float m = in ? srow[lane] : NEG_INIT;
        #pragma unroll
        for (int off = 32; off; off >>= 1) m = fmaxf(m, __shfl_xor(m, off));
        float e = in ? expf(srow[lane] - m) : 0.f;
        if (in) evals[lane] = e;
        float s = e;
        #pragma unroll
        for (int off = 32; off; off >>= 1) s += __shfl_xor(s, off);
        if (lane == 0) {
            float* slot = P + (size_t)(blk + g) * PS;
            slot[0] = m; slot[1] = s;
        }
    }
    __syncthreads();

    // ---- phase 3c: pooling partials from XF (no HBM re-read) ----
    for (int g = gl; g <= gh; ++g) {
        const int r0 = max(start[g], rb), r1 = min(start[g + 1], rb + BM);
        if (r1 <= r0) continue;
        float a = 0.f;
        for (int r = r0; r < r1; ++r)
            a = fmaf(evals[r - rb], XF[r - rb][t], a);
        P[(size_t)(blk + g) * PS + 4 + t] = a;
    }
}

// ---------------------------------------------------------------------------
// k_merge: combine per-block segment partials; one block per group, t = col.
// ---------------------------------------------------------------------------
__global__ __launch_bounds__(512) void k_merge(const float* __restrict__ P,
                                               const int* __restrict__ start,
                                               float* __restrict__ out)
{
    const int g = blockIdx.x, t = threadIdx.x;
    const int s0 = start[g], s1 = start[g + 1];
    if (s0 >= s1) { out[(size_t)g * D + t] = 0.f; return; }
    const int b0 = s0 >> 5, b1 = (s1 - 1) >> 5;   // BM = 32
    float M = NEG_INIT;
    for (int b = b0; b <= b1; ++b)
        M = fmaxf(M, P[(size_t)(b + g) * PS]);
    float den = 0.f, acc = 0.f;
    for (int b = b0; b <= b1; ++b) {
        const float* slot = P + (size_t)(b + g) * PS;
        float w = expf(slot[0] - M);
        den += w * slot[1];
        acc += w * slot[4 + t];
    }
    out[(size_t)g * D + t] = acc / (den + 1e-8f);
}

// ---------------------------------------------------------------------------
extern "C" void kernel_launch(void* const* d_in, const int* in_sizes, int n_in,
                              void* d_out, int out_size, void* d_ws, size_t ws_size,
                              hipStream_t stream) {
    const float* feats = (const float*)d_in[0];
    const int*   index = (const int*)d_in[1];
    const float* Vw = (const float*)d_in[3];
    const float* Vb = (const float*)d_in[4];
    const float* Uw = (const float*)d_in[5];
    const float* Ub = (const float*)d_in[6];
    const float* ww = (const float*)d_in[7];
    float* out = (float*)d_out;

    const int N = in_sizes[1];          // 262144
    const int G = out_size / D;         // 512
    const int nblk = (N + BM - 1) / BM; // 8192

    // ws: Wfrag fp16[256*512] | start[G+1] | (16B align) | P[(nblk+G)*PS]
    _Float16* Wfrag = (_Float16*)d_ws;
    int* start      = (int*)(Wfrag + (size_t)256 * 512);
    size_t off      = (size_t)256 * 512 * 2 + (G + 1) * 4;
    off             = (off + 15) & ~(size_t)15;
    float* P        = (float*)((char*)d_ws + off);

    hipLaunchKernelGGL(k_wprep, dim3(256), dim3(64), 0, stream, Vw, Uw, Wfrag);
    hipLaunchKernelGGL(k_bounds, dim3((G + 1 + 255) / 256), dim3(256), 0, stream,
                       index, N, G, start);
    hipLaunchKernelGGL(k_fused, dim3(nblk), dim3(512), 0, stream,
                       feats, Wfrag, Vb, Ub, ww, index, start, P, N);
    hipLaunchKernelGGL(k_merge, dim3(G), dim3(512), 0, stream, P, start, out);
}